// Round 2
// baseline (229.442 us; speedup 1.0000x reference)
//
#include <hip/hip_runtime.h>
#include <hip/hip_cooperative_groups.h>
#include <math.h>

namespace cg = cooperative_groups;

// Problem constants (B=1)
#define HH 16
#define WW 16
#define DD 16
#define LL 4096          // H*W*Dd
#define CC 48            // d_model
#define DIN 48           // d_inner
#define NN 16            // d_state
#define RR 3             // dt_rank
#define KK 8             // scan directions
#define KD 384           // K*DIN
#define NCH 64           // chunks along L
#define CHL 64           // chunk length

// DPP-based 16-lane (within-row) sum: xor1, xor2 via quad_perm; then
// row_ror:4 + row_ror:8 complete the 16-lane reduction. Pure VALU, no LDS.
__device__ __forceinline__ float dpp_add(float x, const int ctrl_tag) {
    int xi = __float_as_int(x);
    int yi;
    switch (ctrl_tag) {
        case 0: yi = __builtin_amdgcn_update_dpp(0, xi, 0xB1, 0xF, 0xF, true); break; // quad_perm [1,0,3,2]
        case 1: yi = __builtin_amdgcn_update_dpp(0, xi, 0x4E, 0xF, 0xF, true); break; // quad_perm [2,3,0,1]
        case 2: yi = __builtin_amdgcn_update_dpp(0, xi, 0x124, 0xF, 0xF, true); break; // row_ror:4
        default: yi = __builtin_amdgcn_update_dpp(0, xi, 0x128, 0xF, 0xF, true); break; // row_ror:8
    }
    return x + __int_as_float(yi);
}
__device__ __forceinline__ float row16_sum(float p) {
    p = dpp_add(p, 0);
    p = dpp_add(p, 1);
    p = dpp_add(p, 2);
    p = dpp_add(p, 3);
    return p;
}

__device__ __forceinline__ int perm_src(int ll, int kperm) {
    int a = ll >> 8, b2 = (ll >> 4) & 15, c2 = ll & 15;
    switch (kperm) {
        case 0:  return ll;
        case 1:  return b2 * 256 + a * 16 + c2;
        case 2:  return c2 * 256 + b2 * 16 + a;
        default: return a * 256 + c2 * 16 + b2;
    }
}

// ---------------- Kernel 1: in_proj  xz[l,e] = sum_c x[l,c]*W[e,c] ----------
__global__ __launch_bounds__(256) void k_inproj(const float* __restrict__ x,
                                                const float* __restrict__ W,
                                                float* __restrict__ xm,
                                                float* __restrict__ z) {
    int tid = blockIdx.x * 256 + threadIdx.x;          // l*96 + e
    if (tid >= LL * 96) return;
    int e = tid % 96, l = tid / 96;
    const float4* xr = (const float4*)(x + l * CC);
    const float4* wr = (const float4*)(W + e * CC);
    float acc = 0.f;
#pragma unroll
    for (int c4 = 0; c4 < CC / 4; ++c4) {
        float4 a = xr[c4], b = wr[c4];
        acc += a.x * b.x + a.y * b.y + a.z * b.z + a.w * b.w;
    }
    if (e < DIN) xm[e * LL + l] = acc;
    else         z[l * DIN + (e - DIN)] = acc;
}

// ---- Kernel 2: depthwise 3x3x3 conv + bias + SiLU (natural layout only) ----
__global__ __launch_bounds__(256) void k_conv(const float* __restrict__ xm,
                                              const float* __restrict__ cw,
                                              const float* __restrict__ cb,
                                              float* __restrict__ xc) {
    int tid = blockIdx.x * 256 + threadIdx.x;          // d*LL + s
    if (tid >= DIN * LL) return;
    int s = tid & (LL - 1), d = tid >> 12;
    int dd = s & 15, w = (s >> 4) & 15, h = s >> 8;
    const float* wp = cw + d * 27;
    const float* xp = xm + d * LL;
    float acc = 0.f;
#pragma unroll
    for (int i = -1; i <= 1; ++i) {
        int hh = h + i; if (hh < 0 || hh > 15) continue;
#pragma unroll
        for (int j = -1; j <= 1; ++j) {
            int ww2 = w + j; if (ww2 < 0 || ww2 > 15) continue;
#pragma unroll
            for (int q = -1; q <= 1; ++q) {
                int dd2 = dd + q; if (dd2 < 0 || dd2 > 15) continue;
                acc += wp[(i + 1) * 9 + (j + 1) * 3 + (q + 1)]
                     * xp[hh * 256 + ww2 * 16 + dd2];
            }
        }
    }
    acc += cb[d];
    xc[tid] = acc / (1.f + __expf(-acc));              // SiLU
}

// ---- Shared front-end: permuted gather + x_proj GEMM + dt_proj/softplus ----
// 768 threads. Fills xt (u tile, also scratch), xd (x_dbl), ud (u,delta).
__device__ __forceinline__ void frontend(const float* __restrict__ xc,
                                         const float* __restrict__ xpw,
                                         const float* __restrict__ dtw,
                                         const float* __restrict__ dtb,
                                         int k, int l0, int tid,
                                         float* xt, float* xd, float2* ud) {
    int kperm = k & 3, krev = k & 4;
#pragma unroll
    for (int r = 0; r < 4; ++r) {
        int item = r * 768 + tid;                      // 3072 = 48 d * 64 i
        int d = item >> 6, i = item & 63;
        int lg = l0 + i;
        int ll = krev ? (LL - 1 - lg) : lg;
        xt[d * 68 + i] = xc[d * LL + perm_src(ll, kperm)];
    }
    __syncthreads();
    // GEMM: x_dbl[c][l] = sum_d u[d][l] * xpw[k][c][d]
    if (tid < 560) {
        int cc = tid % 35, l4 = tid / 35;
        const float* wr = xpw + (k * 35 + cc) * DIN;   // L1-broadcast
        float4 acc = {0.f, 0.f, 0.f, 0.f};
#pragma unroll
        for (int d2 = 0; d2 < 48; ++d2) {
            float4 v = ((const float4*)(xt + d2 * 68))[l4];
            float w = wr[d2];
            acc.x += v.x * w; acc.y += v.y * w; acc.z += v.z * w; acc.w += v.w * w;
        }
        float* o = xd + cc * 65 + l4 * 4;
        o[0] = acc.x; o[1] = acc.y; o[2] = acc.z; o[3] = acc.w;
    }
    __syncthreads();
    // delta = softplus(dts @ dtw + bias); pack (u,delta) to LDS
#pragma unroll
    for (int r = 0; r < 4; ++r) {
        int item = r * 768 + tid;
        int d2 = item >> 6, l = item & 63;
        int gd = k * DIN + d2;
        float v = xd[l] * dtw[gd * 3] + xd[65 + l] * dtw[gd * 3 + 1]
                + xd[130 + l] * dtw[gd * 3 + 2] + dtb[gd];
        float sp = (v > 20.f) ? v : log1pf(__expf(v));
        ud[d2 * 68 + l] = make_float2(xt[d2 * 68 + l], sp);
    }
    __syncthreads();
}

// ---- Phase 3 + de-permuted store (shared by fused + fallback) --------------
__device__ __forceinline__ void phase3_store(const float2* ud, const float* xd,
                                             float A, float Dv, float hseed,
                                             int d, int n, int tid, int k,
                                             int l0, float* y_t,
                                             float* __restrict__ y2) {
    float h = hseed;
#pragma unroll 8
    for (int i = 0; i < CHL; ++i) {
        float2 uv = ud[d * 68 + i];
        float Bv = xd[(3 + n) * 65 + i];
        float Cv = xd[(19 + n) * 65 + i];
        float dA = __expf(uv.y * A);
        h = h * dA + uv.y * uv.x * Bv;
        float p = row16_sum(h * Cv);                   // pure-VALU 16-lane sum
        if (n == 0) y_t[d * 68 + i] = p + Dv * uv.x;
    }
    __syncthreads();
    // de-permuted store: y2[s][k*48..+47], 192B contiguous per (l)
    int g2 = tid >> 6, l = tid & 63;                   // g2: 0..11
    int lg = l0 + l;
    int ll = (k & 4) ? (LL - 1 - lg) : lg;
    int sp = perm_src(ll, k & 3);
    float4 v;
#pragma unroll
    for (int j = 0; j < 4; ++j) (&v.x)[j] = y_t[(g2 * 4 + j) * 68 + l];
    ((float4*)(y2 + (size_t)sp * KD + k * DIN))[g2] = v;
    __syncthreads();                                   // y_t reused by caller
}

// ---- Kernel 3 (cooperative, 256 blocks x 768 = 1 block/CU): two (k,c)
// pairs per block (k0 and k0+4, same chunk), full scan + LN fused.
// LDS: xt 13.1K + 2*xd 18.2K + 2*ud 52.2K = 81.5 KB -> 1 block/CU always.
// launch_bounds(768,3): VGPR cap 168, trivially met -> cooperative launch
// of 256 blocks (== CU count) cannot fail the co-residency check.
__global__ __launch_bounds__(768, 3) void k_scan_fused(
        const float* __restrict__ xc,  const float* __restrict__ xpw,
        const float* __restrict__ dtw, const float* __restrict__ dtb,
        const float* __restrict__ A_logs, const float* __restrict__ Ds,
        const float* __restrict__ z,   const float* __restrict__ nw,
        const float* __restrict__ nb,  const float* __restrict__ opw,
        float* __restrict__ pa_g, float* __restrict__ hf_g,
        float* __restrict__ y2,   float* __restrict__ out) {
    cg::grid_group grid = cg::this_grid();
    int k0 = blockIdx.x >> 6;                          // 0..3
    int c  = blockIdx.x & (NCH - 1);
    int l0 = c * CHL;
    int tid = threadIdx.x;
    int d = tid >> 4, n = tid & 15;
    __shared__ float  xt[48 * 68];                     // staging / y tile
    __shared__ float  xd0[35 * 65], xd1[35 * 65];
    __shared__ float2 ud0[48 * 68], ud1[48 * 68];

    frontend(xc, xpw, dtw, dtb, k0,     l0, tid, xt, xd0, ud0);
    frontend(xc, xpw, dtw, dtb, k0 + 4, l0, tid, xt, xd1, ud1);

    int gid0 = k0 * DIN + d, gid1 = (k0 + 4) * DIN + d;
    float A0 = -__expf(A_logs[gid0 * NN + n]);
    float A1 = -__expf(A_logs[gid1 * NN + n]);
    // phase 1: local chunk scans (h from 0) for both pairs, interleaved
    {
        float h0 = 0.f, pa0 = 1.f, h1 = 0.f, pa1 = 1.f;
#pragma unroll 4
        for (int i = 0; i < CHL; ++i) {
            float2 u0 = ud0[d * 68 + i];
            float2 u1 = ud1[d * 68 + i];
            float B0 = xd0[(3 + n) * 65 + i];
            float B1 = xd1[(3 + n) * 65 + i];
            float dA0 = __expf(u0.y * A0);
            float dA1 = __expf(u1.y * A1);
            h0 = h0 * dA0 + u0.y * u0.x * B0; pa0 *= dA0;
            h1 = h1 * dA1 + u1.y * u1.x * B1; pa1 *= dA1;
        }
        size_t si0 = (size_t)gid0 * (NCH * 16) + c * 16 + n;
        size_t si1 = (size_t)gid1 * (NCH * 16) + c * 16 + n;
        pa_g[si0] = pa0; hf_g[si0] = h0;
        pa_g[si1] = pa1; hf_g[si1] = h1;
    }

    grid.sync();                                       // summaries visible

    // phase 2 (per-block): h0 seed = combine of chunks [0, c)
    float s0 = 0.f, s1 = 0.f;
    {
        size_t b0 = (size_t)gid0 * (NCH * 16) + n;
        size_t b1 = (size_t)gid1 * (NCH * 16) + n;
        for (int cc = 0; cc < c; ++cc) {
            size_t i0 = b0 + (size_t)cc * 16;
            size_t i1 = b1 + (size_t)cc * 16;
            s0 = s0 * pa_g[i0] + hf_g[i0];             // <=63-step fma chain
            s1 = s1 * pa_g[i1] + hf_g[i1];
        }
    }
    // phase 3: seeded rescans straight from LDS; y tile via xt
    phase3_store(ud0, xd0, A0, Ds[gid0], s0, d, n, tid, k0,     l0, xt, y2);
    phase3_store(ud1, xd1, A1, Ds[gid1], s1, d, n, tid, k0 + 4, l0, xt, y2);

    grid.sync();                                       // y2 visible

    // final: sum dirs + LayerNorm + gate + out_proj. 16 rows/block.
    int wv = tid >> 6, lane = tid & 63;
    float* gbuf = xd0;                                 // xd0 dead, reuse
#pragma unroll
    for (int rep = 0; rep < 2; ++rep) {
        int s = blockIdx.x * 16 + rep * 8 + wv;
        bool act = (wv < 8);
        float val = 0.f;
        if (act && lane < DIN) {
            const float* yp = y2 + (size_t)s * KD + lane;
#pragma unroll
            for (int kk = 0; kk < KK; ++kk) val += yp[kk * DIN];
        }
        float m = val;
#pragma unroll
        for (int o = 32; o >= 1; o >>= 1) m += __shfl_xor(m, o, 64);
        m *= (1.f / 48.f);
        float dvv = (act && lane < DIN) ? (val - m) : 0.f;
        float v2 = dvv * dvv;
#pragma unroll
        for (int o = 32; o >= 1; o >>= 1) v2 += __shfl_xor(v2, o, 64);
        v2 *= (1.f / 48.f);
        float inv = rsqrtf(v2 + 1e-5f);
        if (act && lane < DIN) {
            float yn = dvv * inv * nw[lane] + nb[lane];
            float zz = z[(size_t)s * DIN + lane];
            gbuf[wv * DIN + lane] = yn * (zz / (1.f + __expf(-zz)));
        }
        __syncthreads();
        if (act && lane < DIN) {
            const float* wr = opw + lane * DIN;        // out_proj_w[c, e]
            float acc = 0.f;
#pragma unroll
            for (int e = 0; e < DIN; ++e) acc += gbuf[wv * DIN + e] * wr[e];
            out[(size_t)s * CC + lane] = acc;
        }
        __syncthreads();
    }
}

// =================== Fallback path (non-cooperative split) ==================
// Used only if hipLaunchCooperativeKernel refuses the launch.

__global__ __launch_bounds__(768) void k_scanA(const float* __restrict__ xc,
                                               const float* __restrict__ xpw,
                                               const float* __restrict__ dtw,
                                               const float* __restrict__ dtb,
                                               const float* __restrict__ A_logs,
                                               float* __restrict__ pa_g,
                                               float* __restrict__ hf_g) {
    int k = blockIdx.x >> 6;
    int c = blockIdx.x & (NCH - 1);
    int l0 = c * CHL;
    int tid = threadIdx.x;
    __shared__ float  xt[48 * 68];
    __shared__ float  xd[35 * 65];
    __shared__ float2 ud[48 * 68];
    frontend(xc, xpw, dtw, dtb, k, l0, tid, xt, xd, ud);
    int d = tid >> 4, n = tid & 15;
    int gid = k * DIN + d;
    float A = -__expf(A_logs[gid * NN + n]);
    float h = 0.f, pa = 1.f;
#pragma unroll 8
    for (int i = 0; i < CHL; ++i) {
        float2 uv = ud[d * 68 + i];
        float Bv = xd[(3 + n) * 65 + i];
        float dA = __expf(uv.y * A);
        h = h * dA + uv.y * uv.x * Bv;
        pa *= dA;
    }
    size_t si = (size_t)gid * (NCH * 16) + c * 16 + n;
    pa_g[si] = pa;
    hf_g[si] = h;
}

__global__ __launch_bounds__(256) void k_scan2(const float* __restrict__ pa_g,
                                               const float* __restrict__ hf_g,
                                               float* __restrict__ h0_g) {
    int t = blockIdx.x * 256 + threadIdx.x;            // gid*16 + n
    if (t >= KD * NN) return;
    int n = t & 15;
    int gid = t >> 4;
    size_t base = (size_t)gid * (NCH * 16) + n;
    float h = 0.f;
#pragma unroll 4
    for (int c = 0; c < NCH; ++c) {
        size_t idx = base + (size_t)c * 16;
        h0_g[idx] = h;
        h = h * pa_g[idx] + hf_g[idx];
    }
}

__global__ __launch_bounds__(768) void k_scanB(const float* __restrict__ xc,
                                               const float* __restrict__ xpw,
                                               const float* __restrict__ dtw,
                                               const float* __restrict__ dtb,
                                               const float* __restrict__ A_logs,
                                               const float* __restrict__ Ds,
                                               const float* __restrict__ h0_g,
                                               float* __restrict__ y2) {
    int k = blockIdx.x >> 6;
    int c = blockIdx.x & (NCH - 1);
    int l0 = c * CHL;
    int tid = threadIdx.x;
    __shared__ float  xt[48 * 68];
    __shared__ float  xd[35 * 65];
    __shared__ float2 ud[48 * 68];
    frontend(xc, xpw, dtw, dtb, k, l0, tid, xt, xd, ud);   // recompute
    int d = tid >> 4, n = tid & 15;
    int gid = k * DIN + d;
    float A = -__expf(A_logs[gid * NN + n]);
    float hs = h0_g[(size_t)gid * (NCH * 16) + c * 16 + n];
    phase3_store(ud, xd, A, Ds[gid], hs, d, n, tid, k, l0, xt, y2);
}

__global__ __launch_bounds__(256) void k_final2(const float* __restrict__ y2,
                                                const float* __restrict__ z,
                                                const float* __restrict__ nw,
                                                const float* __restrict__ nb,
                                                const float* __restrict__ opw,
                                                float* __restrict__ out) {
    int wv = threadIdx.x >> 6, lane = threadIdx.x & 63;
    int s = blockIdx.x * 4 + wv;
    __shared__ float g[4][DIN];
    float val = 0.f;
    if (lane < DIN) {
        const float* yp = y2 + (size_t)s * KD + lane;
#pragma unroll
        for (int k = 0; k < KK; ++k) val += yp[k * DIN];
    }
    float m = val;
#pragma unroll
    for (int o = 32; o >= 1; o >>= 1) m += __shfl_xor(m, o, 64);
    m *= (1.f / 48.f);
    float dv = (lane < DIN) ? (val - m) : 0.f;
    float v2 = dv * dv;
#pragma unroll
    for (int o = 32; o >= 1; o >>= 1) v2 += __shfl_xor(v2, o, 64);
    v2 *= (1.f / 48.f);
    float inv = rsqrtf(v2 + 1e-5f);
    if (lane < DIN) {
        float yn = dv * inv * nw[lane] + nb[lane];
        float zz = z[s * DIN + lane];
        g[wv][lane] = yn * (zz / (1.f + __expf(-zz)));
    }
    __syncthreads();
    if (lane < DIN) {
        const float* wr = opw + lane * DIN;            // out_proj_w[c, e]
        float acc = 0.f;
#pragma unroll
        for (int e = 0; e < DIN; ++e) acc += g[wv][e] * wr[e];
        out[s * CC + lane] = acc;
    }
}

extern "C" void kernel_launch(void* const* d_in, const int* in_sizes, int n_in,
                              void* d_out, int out_size, void* d_ws, size_t ws_size,
                              hipStream_t stream) {
    const float* x      = (const float*)d_in[0];
    const float* ipw    = (const float*)d_in[1];
    const float* cw     = (const float*)d_in[2];
    const float* cb     = (const float*)d_in[3];
    const float* xpw    = (const float*)d_in[4];
    const float* dtw    = (const float*)d_in[5];
    const float* dtb    = (const float*)d_in[6];
    const float* A_logs = (const float*)d_in[7];
    const float* Ds     = (const float*)d_in[8];
    const float* nw     = (const float*)d_in[9];
    const float* nb     = (const float*)d_in[10];
    const float* opw    = (const float*)d_in[11];
    float* out = (float*)d_out;

    float* ws   = (float*)d_ws;
    float* xm   = ws;                                  // DIN*LL
    float* z    = xm + DIN * LL;                       // LL*DIN
    float* xc   = z + LL * DIN;                        // DIN*LL
    float* y2   = xc + DIN * LL;                       // LL*KD (s-major)
    float* pa_g = y2 + (size_t)LL * KD;                // KD*NCH*16
    float* hf_g = pa_g + (size_t)KD * NCH * 16;
    float* h0_g = hf_g + (size_t)KD * NCH * 16;        // fallback only

    k_inproj<<<(LL * 96 + 255) / 256, 256, 0, stream>>>(x, ipw, xm, z);
    k_conv<<<(DIN * LL + 255) / 256, 256, 0, stream>>>(xm, cw, cb, xc);

    void* args[] = {(void*)&xc, (void*)&xpw, (void*)&dtw, (void*)&dtb,
                    (void*)&A_logs, (void*)&Ds, (void*)&z, (void*)&nw,
                    (void*)&nb, (void*)&opw, (void*)&pa_g, (void*)&hf_g,
                    (void*)&y2, (void*)&out};
    hipError_t ce = hipLaunchCooperativeKernel((void*)k_scan_fused,
                                               dim3(256), dim3(768),
                                               args, 0, stream);
    if (ce != hipSuccess) {
        // Non-cooperative fallback: split at the two grid.sync points.
        k_scanA<<<KK * NCH, 768, 0, stream>>>(xc, xpw, dtw, dtb, A_logs,
                                              pa_g, hf_g);
        k_scan2<<<(KD * NN + 255) / 256, 256, 0, stream>>>(pa_g, hf_g, h0_g);
        k_scanB<<<KK * NCH, 768, 0, stream>>>(xc, xpw, dtw, dtb, A_logs, Ds,
                                              h0_g, y2);
        k_final2<<<LL / 4, 256, 0, stream>>>(y2, z, nw, nb, opw, out);
    }
}

// Round 3
// 164.534 us; speedup vs baseline: 1.3945x; 1.3945x over previous
//
#include <hip/hip_runtime.h>
#include <hip/hip_bf16.h>
#include <math.h>

// Problem constants (B=1)
#define HH 16
#define WW 16
#define DD 16
#define LL 4096          // H*W*Dd
#define CC 48            // d_model
#define DIN 48           // d_inner
#define NN 16            // d_state
#define RR 3             // dt_rank
#define KK 8             // scan directions
#define KD 384           // K*DIN
#define NCH 64           // chunks along L
#define CHL 64           // chunk length

// DPP-based 16-lane (within-row) sum: xor1, xor2 via quad_perm; then
// row_ror:4 + row_ror:8 complete the 16-lane reduction. Pure VALU, no LDS.
__device__ __forceinline__ float dpp_add(float x, const int ctrl_tag) {
    int xi = __float_as_int(x);
    int yi;
    switch (ctrl_tag) {
        case 0: yi = __builtin_amdgcn_update_dpp(0, xi, 0xB1, 0xF, 0xF, true); break; // quad_perm [1,0,3,2]
        case 1: yi = __builtin_amdgcn_update_dpp(0, xi, 0x4E, 0xF, 0xF, true); break; // quad_perm [2,3,0,1]
        case 2: yi = __builtin_amdgcn_update_dpp(0, xi, 0x124, 0xF, 0xF, true); break; // row_ror:4
        default: yi = __builtin_amdgcn_update_dpp(0, xi, 0x128, 0xF, 0xF, true); break; // row_ror:8
    }
    return x + __int_as_float(yi);
}
__device__ __forceinline__ float row16_sum(float p) {
    p = dpp_add(p, 0);
    p = dpp_add(p, 1);
    p = dpp_add(p, 2);
    p = dpp_add(p, 3);
    return p;
}

// ---------------- Kernel 1: in_proj  xz[l,e] = sum_c x[l,c]*W[e,c] ----------
__global__ __launch_bounds__(256) void k_inproj(const float* __restrict__ x,
                                                const float* __restrict__ W,
                                                float* __restrict__ xm,
                                                float* __restrict__ z) {
    int tid = blockIdx.x * 256 + threadIdx.x;          // l*96 + e
    if (tid >= LL * 96) return;
    int e = tid % 96, l = tid / 96;
    const float4* xr = (const float4*)(x + l * CC);
    const float4* wr = (const float4*)(W + e * CC);
    float acc = 0.f;
#pragma unroll
    for (int c4 = 0; c4 < CC / 4; ++c4) {
        float4 a = xr[c4], b = wr[c4];
        acc += a.x * b.x + a.y * b.y + a.z * b.z + a.w * b.w;
    }
    if (e < DIN) xm[e * LL + l] = acc;
    else         z[l * DIN + (e - DIN)] = acc;
}

// ---- Kernel 2: depthwise 3x3x3 conv + bias + SiLU (natural layout only) ----
__global__ __launch_bounds__(256) void k_conv(const float* __restrict__ xm,
                                              const float* __restrict__ cw,
                                              const float* __restrict__ cb,
                                              float* __restrict__ xc) {
    int tid = blockIdx.x * 256 + threadIdx.x;          // d*LL + s
    if (tid >= DIN * LL) return;
    int s = tid & (LL - 1), d = tid >> 12;
    int dd = s & 15, w = (s >> 4) & 15, h = s >> 8;
    const float* wp = cw + d * 27;
    const float* xp = xm + d * LL;
    float acc = 0.f;
#pragma unroll
    for (int i = -1; i <= 1; ++i) {
        int hh = h + i; if (hh < 0 || hh > 15) continue;
#pragma unroll
        for (int j = -1; j <= 1; ++j) {
            int ww2 = w + j; if (ww2 < 0 || ww2 > 15) continue;
#pragma unroll
            for (int q = -1; q <= 1; ++q) {
                int dd2 = dd + q; if (dd2 < 0 || dd2 > 15) continue;
                acc += wp[(i + 1) * 9 + (j + 1) * 3 + (q + 1)]
                     * xp[hh * 256 + ww2 * 16 + dd2];
            }
        }
    }
    acc += cb[d];
    xc[tid] = acc / (1.f + __expf(-acc));              // SiLU
}

// ---- Kernel 3: permuted gather + x_proj + dt_proj + scan PHASE 1. ----------
// Block per (k, chunk), 768 thr = 48 d x 16 n. u gathered from xc via the
// direction permutation (once). Emits BC, packed ud=(u,delta), phf=(pa,hf).
__global__ __launch_bounds__(768) void k_xscan1(const float* __restrict__ xc,
                                                const float* __restrict__ xpw,
                                                const float* __restrict__ dtw,
                                                const float* __restrict__ dtb,
                                                const float* __restrict__ A_logs,
                                                float* __restrict__ BC,
                                                float* __restrict__ ud_g,
                                                float* __restrict__ phf_g) {
    int k = blockIdx.x >> 6;
    int c = blockIdx.x & (NCH - 1);
    int l0 = c * CHL;
    int tid = threadIdx.x;
    __shared__ float xt[48 * 68];                      // u tile [d][64]
    __shared__ float xd[35 * 65];                      // x_dbl [c][64]
    __shared__ float2 ud[48 * 68];                     // (u, delta)
    int kperm = k & 3, krev = k & 4;
    // stage u tile via permuted gather from natural-layout xc
#pragma unroll
    for (int r = 0; r < 4; ++r) {
        int item = r * 768 + tid;                      // 3072 = 48 d * 64 i
        int d = item >> 6, i = item & 63;
        int lg = l0 + i;
        int ll = krev ? (LL - 1 - lg) : lg;
        int a = ll >> 8, b2 = (ll >> 4) & 15, c2 = ll & 15;
        int src;
        switch (kperm) {
            case 0: src = ll;                       break;
            case 1: src = b2 * 256 + a * 16 + c2;   break;
            case 2: src = c2 * 256 + b2 * 16 + a;   break;
            default: src = a * 256 + c2 * 16 + b2;  break;
        }
        xt[d * 68 + i] = xc[d * LL + src];
    }
    __syncthreads();
    // GEMM: x_dbl[c][l] = sum_d u[d][l] * xpw[k][c][d]
    if (tid < 560) {
        int cc = tid % 35, l4 = tid / 35;
        const float* wr = xpw + (k * 35 + cc) * DIN;   // L1-broadcast
        float4 acc = {0.f, 0.f, 0.f, 0.f};
#pragma unroll
        for (int d2 = 0; d2 < 48; ++d2) {
            float4 v = ((const float4*)(xt + d2 * 68))[l4];
            float w = wr[d2];
            acc.x += v.x * w; acc.y += v.y * w; acc.z += v.z * w; acc.w += v.w * w;
        }
        float* o = xd + cc * 65 + l4 * 4;
        o[0] = acc.x; o[1] = acc.y; o[2] = acc.z; o[3] = acc.w;
    }
    __syncthreads();
    // BC write (float4 over 32 cols)
    if (tid < 512) {
        int l = tid >> 3, q = tid & 7;
        float4 v;
#pragma unroll
        for (int j = 0; j < 4; ++j) (&v.x)[j] = xd[(3 + q * 4 + j) * 65 + l];
        ((float4*)(BC + ((size_t)(k * LL + l0 + l)) * 32))[q] = v;
    }
    // delta = softplus(dts @ dtw + bias); pack (u,delta) to LDS + global
#pragma unroll
    for (int r = 0; r < 4; ++r) {
        int item = r * 768 + tid;
        int d2 = item >> 6, l = item & 63;
        int gd = k * DIN + d2;
        float v = xd[l] * dtw[gd * 3] + xd[65 + l] * dtw[gd * 3 + 1]
                + xd[130 + l] * dtw[gd * 3 + 2] + dtb[gd];
        float sp = (v > 20.f) ? v : log1pf(__expf(v));
        float u = xt[d2 * 68 + l];
        float2 p = make_float2(u, sp);
        ud[d2 * 68 + l] = p;
        ((float2*)ud_g)[(size_t)gd * LL + l0 + l] = p;
    }
    __syncthreads();
    // scan phase 1: local chunk scan (h starts at 0) -> packed (pa, hf)
    int d = tid >> 4, n = tid & 15;
    int gid = k * DIN + d;
    float A = -__expf(A_logs[gid * NN + n]);
    float h = 0.f, pa = 1.f;
#pragma unroll 8
    for (int i = 0; i < CHL; ++i) {
        float2 uv = ud[d * 68 + i];
        float Bv = xd[(3 + n) * 65 + i];
        float dA = __expf(uv.y * A);
        h = h * dA + uv.y * uv.x * Bv;
        pa *= dA;
    }
    size_t si = (size_t)gid * (NCH * 16) + c * 16 + n;
    ((float2*)phf_g)[si] = make_float2(pa, h);
}

// ---- Kernel 4: scan PHASE 2+3 fused — per-block seed chain, then seeded
// re-scan with DPP reduce and de-permuted y2 store. The former dedicated
// serial-combine kernel (24 CUs busy, 232 idle, 2 device drains) is replaced
// by a <=63-step fma chain per block over the L2/L3-resident packed (pa,hf)
// summaries, overlapped across all 512 blocks at 2 blocks/CU.
__global__ __launch_bounds__(768) void k_scan3(const float* __restrict__ ud_g,
                                               const float* __restrict__ BC,
                                               const float* __restrict__ A_logs,
                                               const float* __restrict__ Ds,
                                               const float* __restrict__ phf_g,
                                               float* __restrict__ y2) {
    int k = blockIdx.x >> 6;
    int c = blockIdx.x & (NCH - 1);
    int l0 = c * CHL;
    int tid = threadIdx.x;
    int d = tid >> 4, n = tid & 15;
    int gid = k * DIN + d;
    __shared__ float y_t[48 * 68];
    float A = -__expf(A_logs[gid * NN + n]);
    float Dv = Ds[gid];
    // phase 2 (folded): h seed = exclusive combine of chunks [0, c)
    float h = 0.f;
    {
        const float2* pp = ((const float2*)phf_g) + (size_t)gid * (NCH * 16) + n;
        for (int cc = 0; cc < c; ++cc) {
            float2 v = pp[cc * 16];
            h = h * v.x + v.y;                         // dependent fma chain
        }
    }
    const float2* up = ((const float2*)ud_g) + (size_t)gid * LL + l0;
    const float* bp = BC + ((size_t)(k * LL + l0)) * 32 + n;
    const float* cp = bp + 16;
#pragma unroll 8
    for (int i = 0; i < CHL; ++i) {
        float2 uv = up[i];
        float Bv = bp[(size_t)i * 32];
        float Cv = cp[(size_t)i * 32];
        float dA = __expf(uv.y * A);
        h = h * dA + uv.y * uv.x * Bv;
        float p = row16_sum(h * Cv);                   // pure-VALU 16-lane sum
        if (n == 0) y_t[d * 68 + i] = p + Dv * uv.x;
    }
    __syncthreads();
    // de-permuted store: y2[s][k*48..+47], 192B contiguous per (l)
    {
        int g = tid >> 6, l = tid & 63;                // g: 0..11
        int lg = l0 + l;
        int ll = (k & 4) ? (LL - 1 - lg) : lg;
        int a = ll >> 8, b2 = (ll >> 4) & 15, c2 = ll & 15;
        int s;
        switch (k & 3) {
            case 0: s = ll;                        break;
            case 1: s = b2 * 256 + a * 16 + c2;    break;
            case 2: s = c2 * 256 + b2 * 16 + a;    break;
            default: s = a * 256 + c2 * 16 + b2;   break;
        }
        float4 v;
#pragma unroll
        for (int j = 0; j < 4; ++j) (&v.x)[j] = y_t[(g * 4 + j) * 68 + l];
        ((float4*)(y2 + (size_t)s * KD + k * DIN))[g] = v;
    }
}

// ---- Kernel 5: sum dirs + LayerNorm + gate + out_proj. Wave per s. ---------
__global__ __launch_bounds__(256) void k_final2(const float* __restrict__ y2,
                                                const float* __restrict__ z,
                                                const float* __restrict__ nw,
                                                const float* __restrict__ nb,
                                                const float* __restrict__ opw,
                                                float* __restrict__ out) {
    int wv = threadIdx.x >> 6, lane = threadIdx.x & 63;
    int s = blockIdx.x * 4 + wv;
    __shared__ float g[4][DIN];
    float val = 0.f;
    if (lane < DIN) {
        const float* yp = y2 + (size_t)s * KD + lane;
#pragma unroll
        for (int k = 0; k < KK; ++k) val += yp[k * DIN];
    }
    float m = val;
#pragma unroll
    for (int o = 32; o >= 1; o >>= 1) m += __shfl_xor(m, o, 64);
    m *= (1.f / 48.f);
    float dv = (lane < DIN) ? (val - m) : 0.f;
    float v2 = dv * dv;
#pragma unroll
    for (int o = 32; o >= 1; o >>= 1) v2 += __shfl_xor(v2, o, 64);
    v2 *= (1.f / 48.f);
    float inv = rsqrtf(v2 + 1e-5f);
    if (lane < DIN) {
        float yn = dv * inv * nw[lane] + nb[lane];
        float zz = z[s * DIN + lane];
        g[wv][lane] = yn * (zz / (1.f + __expf(-zz)));
    }
    __syncthreads();
    if (lane < DIN) {
        const float* wr = opw + lane * DIN;            // out_proj_w[c, e]
        float acc = 0.f;
#pragma unroll
        for (int e = 0; e < DIN; ++e) acc += g[wv][e] * wr[e];
        out[s * CC + lane] = acc;
    }
}

extern "C" void kernel_launch(void* const* d_in, const int* in_sizes, int n_in,
                              void* d_out, int out_size, void* d_ws, size_t ws_size,
                              hipStream_t stream) {
    const float* x      = (const float*)d_in[0];
    const float* ipw    = (const float*)d_in[1];
    const float* cw     = (const float*)d_in[2];
    const float* cb     = (const float*)d_in[3];
    const float* xpw    = (const float*)d_in[4];
    const float* dtw    = (const float*)d_in[5];
    const float* dtb    = (const float*)d_in[6];
    const float* A_logs = (const float*)d_in[7];
    const float* Ds     = (const float*)d_in[8];
    const float* nw     = (const float*)d_in[9];
    const float* nb     = (const float*)d_in[10];
    const float* opw    = (const float*)d_in[11];
    float* out = (float*)d_out;

    float* ws    = (float*)d_ws;
    float* xm    = ws;                                 // DIN*LL
    float* z     = xm + DIN * LL;                      // LL*DIN
    float* xc    = z + LL * DIN;                       // DIN*LL
    float* ud_g  = xc + DIN * LL;                      // 2*KD*LL (float2)
    float* BC    = ud_g + (size_t)2 * KD * LL;         // KK*LL*32
    float* y2    = BC + (size_t)KK * LL * 32;          // LL*KD (s-major)
    float* phf_g = y2 + (size_t)LL * KD;               // 2*KD*NCH*16 (float2)

    k_inproj<<<(LL * 96 + 255) / 256, 256, 0, stream>>>(x, ipw, xm, z);
    k_conv<<<(DIN * LL + 255) / 256, 256, 0, stream>>>(xm, cw, cb, xc);
    k_xscan1<<<KK * NCH, 768, 0, stream>>>(xc, xpw, dtw, dtb, A_logs,
                                           BC, ud_g, phf_g);
    k_scan3<<<KK * NCH, 768, 0, stream>>>(ud_g, BC, A_logs, Ds, phf_g, y2);
    k_final2<<<LL / 4, 256, 0, stream>>>(y2, z, nw, nb, opw, out);
}

// Round 4
// 143.186 us; speedup vs baseline: 1.6024x; 1.1491x over previous
//
#include <hip/hip_runtime.h>
#include <hip/hip_bf16.h>
#include <math.h>

// Problem constants (B=1)
#define HH 16
#define WW 16
#define DD 16
#define LL 4096          // H*W*Dd
#define CC 48            // d_model
#define DIN 48           // d_inner
#define NN 16            // d_state
#define RR 3             // dt_rank
#define KK 8             // scan directions
#define KD 384           // K*DIN
#define NCH 64           // chunks along L
#define CHL 64           // chunk length

// DPP-based 16-lane (within-row) sum: xor1, xor2 via quad_perm; then
// row_ror:4 + row_ror:8 complete the 16-lane reduction. Pure VALU, no LDS.
__device__ __forceinline__ float dpp_add(float x, const int ctrl_tag) {
    int xi = __float_as_int(x);
    int yi;
    switch (ctrl_tag) {
        case 0: yi = __builtin_amdgcn_update_dpp(0, xi, 0xB1, 0xF, 0xF, true); break; // quad_perm [1,0,3,2]
        case 1: yi = __builtin_amdgcn_update_dpp(0, xi, 0x4E, 0xF, 0xF, true); break; // quad_perm [2,3,0,1]
        case 2: yi = __builtin_amdgcn_update_dpp(0, xi, 0x124, 0xF, 0xF, true); break; // row_ror:4
        default: yi = __builtin_amdgcn_update_dpp(0, xi, 0x128, 0xF, 0xF, true); break; // row_ror:8
    }
    return x + __int_as_float(yi);
}
__device__ __forceinline__ float row16_sum(float p) {
    p = dpp_add(p, 0);
    p = dpp_add(p, 1);
    p = dpp_add(p, 2);
    p = dpp_add(p, 3);
    return p;
}

// ---------------- Kernel 1: in_proj  xz[l,e] = sum_c x[l,c]*W[e,c] ----------
__global__ __launch_bounds__(256) void k_inproj(const float* __restrict__ x,
                                                const float* __restrict__ W,
                                                float* __restrict__ xm,
                                                float* __restrict__ z) {
    int tid = blockIdx.x * 256 + threadIdx.x;          // l*96 + e
    if (tid >= LL * 96) return;
    int e = tid % 96, l = tid / 96;
    const float4* xr = (const float4*)(x + l * CC);
    const float4* wr = (const float4*)(W + e * CC);
    float acc = 0.f;
#pragma unroll
    for (int c4 = 0; c4 < CC / 4; ++c4) {
        float4 a = xr[c4], b = wr[c4];
        acc += a.x * b.x + a.y * b.y + a.z * b.z + a.w * b.w;
    }
    if (e < DIN) xm[e * LL + l] = acc;
    else         z[l * DIN + (e - DIN)] = acc;
}

// ---- Kernel 2: depthwise 3x3x3 conv + bias + SiLU (natural layout only) ----
__global__ __launch_bounds__(256) void k_conv(const float* __restrict__ xm,
                                              const float* __restrict__ cw,
                                              const float* __restrict__ cb,
                                              float* __restrict__ xc) {
    int tid = blockIdx.x * 256 + threadIdx.x;          // d*LL + s
    if (tid >= DIN * LL) return;
    int s = tid & (LL - 1), d = tid >> 12;
    int dd = s & 15, w = (s >> 4) & 15, h = s >> 8;
    const float* wp = cw + d * 27;
    const float* xp = xm + d * LL;
    float acc = 0.f;
#pragma unroll
    for (int i = -1; i <= 1; ++i) {
        int hh = h + i; if (hh < 0 || hh > 15) continue;
#pragma unroll
        for (int j = -1; j <= 1; ++j) {
            int ww2 = w + j; if (ww2 < 0 || ww2 > 15) continue;
#pragma unroll
            for (int q = -1; q <= 1; ++q) {
                int dd2 = dd + q; if (dd2 < 0 || dd2 > 15) continue;
                acc += wp[(i + 1) * 9 + (j + 1) * 3 + (q + 1)]
                     * xp[hh * 256 + ww2 * 16 + dd2];
            }
        }
    }
    acc += cb[d];
    xc[tid] = acc / (1.f + __expf(-acc));              // SiLU
}

// ---- Kernel 3: permuted gather + x_proj + dt_proj + scan PHASE 1. ----------
// Block per (k, chunk), 768 thr = 48 d x 16 n. u gathered from xc via the
// direction permutation (once). Emits BC, packed ud=(u,delta), phf=(pa,hf).
__global__ __launch_bounds__(768) void k_xscan1(const float* __restrict__ xc,
                                                const float* __restrict__ xpw,
                                                const float* __restrict__ dtw,
                                                const float* __restrict__ dtb,
                                                const float* __restrict__ A_logs,
                                                float* __restrict__ BC,
                                                float* __restrict__ ud_g,
                                                float* __restrict__ phf_g) {
    int k = blockIdx.x >> 6;
    int c = blockIdx.x & (NCH - 1);
    int l0 = c * CHL;
    int tid = threadIdx.x;
    __shared__ float xt[48 * 68];                      // u tile [d][64]
    __shared__ float xd[35 * 65];                      // x_dbl [c][64]
    __shared__ float2 ud[48 * 68];                     // (u, delta)
    int kperm = k & 3, krev = k & 4;
    // stage u tile via permuted gather from natural-layout xc
#pragma unroll
    for (int r = 0; r < 4; ++r) {
        int item = r * 768 + tid;                      // 3072 = 48 d * 64 i
        int d = item >> 6, i = item & 63;
        int lg = l0 + i;
        int ll = krev ? (LL - 1 - lg) : lg;
        int a = ll >> 8, b2 = (ll >> 4) & 15, c2 = ll & 15;
        int src;
        switch (kperm) {
            case 0: src = ll;                       break;
            case 1: src = b2 * 256 + a * 16 + c2;   break;
            case 2: src = c2 * 256 + b2 * 16 + a;   break;
            default: src = a * 256 + c2 * 16 + b2;  break;
        }
        xt[d * 68 + i] = xc[d * LL + src];
    }
    __syncthreads();
    // GEMM: x_dbl[c][l] = sum_d u[d][l] * xpw[k][c][d]
    if (tid < 560) {
        int cc = tid % 35, l4 = tid / 35;
        const float* wr = xpw + (k * 35 + cc) * DIN;   // L1-broadcast
        float4 acc = {0.f, 0.f, 0.f, 0.f};
#pragma unroll
        for (int d2 = 0; d2 < 48; ++d2) {
            float4 v = ((const float4*)(xt + d2 * 68))[l4];
            float w = wr[d2];
            acc.x += v.x * w; acc.y += v.y * w; acc.z += v.z * w; acc.w += v.w * w;
        }
        float* o = xd + cc * 65 + l4 * 4;
        o[0] = acc.x; o[1] = acc.y; o[2] = acc.z; o[3] = acc.w;
    }
    __syncthreads();
    // BC write (float4 over 32 cols)
    if (tid < 512) {
        int l = tid >> 3, q = tid & 7;
        float4 v;
#pragma unroll
        for (int j = 0; j < 4; ++j) (&v.x)[j] = xd[(3 + q * 4 + j) * 65 + l];
        ((float4*)(BC + ((size_t)(k * LL + l0 + l)) * 32))[q] = v;
    }
    // delta = softplus(dts @ dtw + bias); pack (u,delta) to LDS + global
#pragma unroll
    for (int r = 0; r < 4; ++r) {
        int item = r * 768 + tid;
        int d2 = item >> 6, l = item & 63;
        int gd = k * DIN + d2;
        float v = xd[l] * dtw[gd * 3] + xd[65 + l] * dtw[gd * 3 + 1]
                + xd[130 + l] * dtw[gd * 3 + 2] + dtb[gd];
        float sp = (v > 20.f) ? v : log1pf(__expf(v));
        float u = xt[d2 * 68 + l];
        float2 p = make_float2(u, sp);
        ud[d2 * 68 + l] = p;
        ((float2*)ud_g)[(size_t)gd * LL + l0 + l] = p;
    }
    __syncthreads();
    // scan phase 1: local chunk scan (h starts at 0) -> packed (pa, hf)
    int d = tid >> 4, n = tid & 15;
    int gid = k * DIN + d;
    float A = -__expf(A_logs[gid * NN + n]);
    float h = 0.f, pa = 1.f;
#pragma unroll 8
    for (int i = 0; i < CHL; ++i) {
        float2 uv = ud[d * 68 + i];
        float Bv = xd[(3 + n) * 65 + i];
        float dA = __expf(uv.y * A);
        h = h * dA + uv.y * uv.x * Bv;
        pa *= dA;
    }
    size_t si = (size_t)gid * (NCH * 16) + c * 16 + n;
    ((float2*)phf_g)[si] = make_float2(pa, h);
}

// ---- Kernel 4: scan PHASE 2+3 fused, LDS-staged. ---------------------------
// Round-3 showed this kernel latency-bound (45.5us, VALUBusy 22.8%, HBM 7%):
// the 64-step dependent recurrence read ud_g/BC straight from global (32
// useful B/wave per ud load) and the compiler (VGPR=40) pipelined nothing.
// v2: bulk-stage the chunk's (u,delta) 24KB + BC 8KB into LDS with coalesced
// float4 loads (3/thread, full MLP), 8-way-MLP the seed chain, then run the
// recurrence entirely from LDS. 45.8KB LDS/block; launch_bounds(768,6)
// guarantees VGPR<=84 so 2 blocks/CU (24 waves) stay co-resident.
__global__ __launch_bounds__(768, 6) void k_scan3(const float* __restrict__ ud_g,
                                                  const float* __restrict__ BC,
                                                  const float* __restrict__ A_logs,
                                                  const float* __restrict__ Ds,
                                                  const float* __restrict__ phf_g,
                                                  float* __restrict__ y2) {
    int k = blockIdx.x >> 6;
    int c = blockIdx.x & (NCH - 1);
    int l0 = c * CHL;
    int tid = threadIdx.x;
    int d = tid >> 4, n = tid & 15;
    int gid = k * DIN + d;
    __shared__ float2 s_ud[48 * 64];                   // (u,delta) [d][i]
    __shared__ float  s_bc[64 * 32];                   // B,C [i][32]
    __shared__ float  y_t[48 * 68];

    // --- bulk staging: 1536 float4 of ud + 512 float4 of BC, coalesced
    const float4* ud4 = (const float4*)ud_g;
    const float4* bc4 = (const float4*)BC;
    int r0 = tid >> 5, q0 = tid & 31;                  // ud: row 0..47, col 0..31
    float4 ua = ud4[(size_t)(k * DIN + r0)      * (LL / 2) + (l0 / 2) + q0];
    float4 ub = ud4[(size_t)(k * DIN + 24 + r0) * (LL / 2) + (l0 / 2) + q0];
    float4 bv;
    if (tid < 512) bv = bc4[((size_t)(k * LL + l0 + (tid >> 3))) * 8 + (tid & 7)];
    ((float4*)s_ud)[tid] = ua;
    ((float4*)s_ud)[768 + tid] = ub;
    if (tid < 512) ((float4*)s_bc)[tid] = bv;

    float A = -__expf(A_logs[gid * NN + n]);
    float Dv = Ds[gid];

    // --- seed: exclusive combine of chunks [0, c); 8 independent loads/group
    float h = 0.f;
    {
        const float2* pp = ((const float2*)phf_g) + (size_t)gid * (NCH * 16) + n;
        int cc = 0;
        for (; cc + 8 <= c; cc += 8) {
            float2 v0 = pp[(cc + 0) * 16]; float2 v1 = pp[(cc + 1) * 16];
            float2 v2 = pp[(cc + 2) * 16]; float2 v3 = pp[(cc + 3) * 16];
            float2 v4 = pp[(cc + 4) * 16]; float2 v5 = pp[(cc + 5) * 16];
            float2 v6 = pp[(cc + 6) * 16]; float2 v7 = pp[(cc + 7) * 16];
            h = h * v0.x + v0.y; h = h * v1.x + v1.y;
            h = h * v2.x + v2.y; h = h * v3.x + v3.y;
            h = h * v4.x + v4.y; h = h * v5.x + v5.y;
            h = h * v6.x + v6.y; h = h * v7.x + v7.y;
        }
        for (; cc < c; ++cc) { float2 v = pp[cc * 16]; h = h * v.x + v.y; }
    }
    __syncthreads();                                   // staging visible

    // --- seeded re-scan, fully LDS-fed
    const float2* ur = s_ud + d * 64;
#pragma unroll 8
    for (int i = 0; i < CHL; ++i) {
        float2 uv = ur[i];
        float Bv = s_bc[i * 32 + n];
        float Cv = s_bc[i * 32 + 16 + n];
        float dA = __expf(uv.y * A);
        h = h * dA + uv.y * uv.x * Bv;
        float p = row16_sum(h * Cv);                   // pure-VALU 16-lane sum
        if (n == 0) y_t[d * 68 + i] = p + Dv * uv.x;
    }
    __syncthreads();
    // de-permuted store: y2[s][k*48..+47], 192B contiguous per (l)
    {
        int g = tid >> 6, l = tid & 63;                // g: 0..11
        int lg = l0 + l;
        int ll = (k & 4) ? (LL - 1 - lg) : lg;
        int a = ll >> 8, b2 = (ll >> 4) & 15, c2 = ll & 15;
        int s;
        switch (k & 3) {
            case 0: s = ll;                        break;
            case 1: s = b2 * 256 + a * 16 + c2;    break;
            case 2: s = c2 * 256 + b2 * 16 + a;    break;
            default: s = a * 256 + c2 * 16 + b2;   break;
        }
        float4 v;
#pragma unroll
        for (int j = 0; j < 4; ++j) (&v.x)[j] = y_t[(g * 4 + j) * 68 + l];
        ((float4*)(y2 + (size_t)s * KD + k * DIN))[g] = v;
    }
}

// ---- Kernel 5: sum dirs + LayerNorm + gate + out_proj. Wave per s. ---------
__global__ __launch_bounds__(256) void k_final2(const float* __restrict__ y2,
                                                const float* __restrict__ z,
                                                const float* __restrict__ nw,
                                                const float* __restrict__ nb,
                                                const float* __restrict__ opw,
                                                float* __restrict__ out) {
    int wv = threadIdx.x >> 6, lane = threadIdx.x & 63;
    int s = blockIdx.x * 4 + wv;
    __shared__ float g[4][DIN];
    float val = 0.f;
    if (lane < DIN) {
        const float* yp = y2 + (size_t)s * KD + lane;
#pragma unroll
        for (int k = 0; k < KK; ++k) val += yp[k * DIN];
    }
    float m = val;
#pragma unroll
    for (int o = 32; o >= 1; o >>= 1) m += __shfl_xor(m, o, 64);
    m *= (1.f / 48.f);
    float dv = (lane < DIN) ? (val - m) : 0.f;
    float v2 = dv * dv;
#pragma unroll
    for (int o = 32; o >= 1; o >>= 1) v2 += __shfl_xor(v2, o, 64);
    v2 *= (1.f / 48.f);
    float inv = rsqrtf(v2 + 1e-5f);
    if (lane < DIN) {
        float yn = dv * inv * nw[lane] + nb[lane];
        float zz = z[s * DIN + lane];
        g[wv][lane] = yn * (zz / (1.f + __expf(-zz)));
    }
    __syncthreads();
    if (lane < DIN) {
        const float* wr = opw + lane * DIN;            // out_proj_w[c, e]
        float acc = 0.f;
#pragma unroll
        for (int e = 0; e < DIN; ++e) acc += g[wv][e] * wr[e];
        out[s * CC + lane] = acc;
    }
}

extern "C" void kernel_launch(void* const* d_in, const int* in_sizes, int n_in,
                              void* d_out, int out_size, void* d_ws, size_t ws_size,
                              hipStream_t stream) {
    const float* x      = (const float*)d_in[0];
    const float* ipw    = (const float*)d_in[1];
    const float* cw     = (const float*)d_in[2];
    const float* cb     = (const float*)d_in[3];
    const float* xpw    = (const float*)d_in[4];
    const float* dtw    = (const float*)d_in[5];
    const float* dtb    = (const float*)d_in[6];
    const float* A_logs = (const float*)d_in[7];
    const float* Ds     = (const float*)d_in[8];
    const float* nw     = (const float*)d_in[9];
    const float* nb     = (const float*)d_in[10];
    const float* opw    = (const float*)d_in[11];
    float* out = (float*)d_out;

    float* ws    = (float*)d_ws;
    float* xm    = ws;                                 // DIN*LL
    float* z     = xm + DIN * LL;                      // LL*DIN
    float* xc    = z + LL * DIN;                       // DIN*LL
    float* ud_g  = xc + DIN * LL;                      // 2*KD*LL (float2)
    float* BC    = ud_g + (size_t)2 * KD * LL;         // KK*LL*32
    float* y2    = BC + (size_t)KK * LL * 32;          // LL*KD (s-major)
    float* phf_g = y2 + (size_t)LL * KD;               // 2*KD*NCH*16 (float2)

    k_inproj<<<(LL * 96 + 255) / 256, 256, 0, stream>>>(x, ipw, xm, z);
    k_conv<<<(DIN * LL + 255) / 256, 256, 0, stream>>>(xm, cw, cb, xc);
    k_xscan1<<<KK * NCH, 768, 0, stream>>>(xc, xpw, dtw, dtb, A_logs,
                                           BC, ud_g, phf_g);
    k_scan3<<<KK * NCH, 768, 0, stream>>>(ud_g, BC, A_logs, Ds, phf_g, y2);
    k_final2<<<LL / 4, 256, 0, stream>>>(y2, z, nw, nb, opw, out);
}